// Round 7
// baseline (531.018 us; speedup 1.0000x reference)
//
#include <hip/hip_runtime.h>

#define CC 256
#define HH 256
#define WW 256
#define HWV 65536
#define NN 4096
#define CG 16     // channels per fused-gather block
#define NBAND 16  // 16 bands of 16 rows

using u64 = unsigned long long;
using u32 = unsigned int;

__device__ __forceinline__ u32 lbound(const u32* __restrict__ a, u32 n, u32 key) {
    u32 lo = 0, hi = n;
    while (lo < hi) { u32 mid = (lo + hi) >> 1; if (a[mid] < key) lo = mid + 1; else hi = mid; }
    return lo;
}

// ---------------------------------------------------------------------------
// K1: 48-bit sortable keys: (monotone(float) << 16) | (0xFFFF - pix).
// Distinct per pixel; descending key order == lax.top_k order.
__global__ void build_keys_k(const float* __restrict__ pm, const int* __restrict__ em,
                             u64* __restrict__ keys) {
    int i = blockIdx.x * blockDim.x + threadIdx.x;   // b*65536 + pix
    float f = (em[i] == 1) ? -fabsf(pm[i]) : -1e30f;
    u32 u = __float_as_uint(f);
    u32 k = (u & 0x80000000u) ? ~u : (u | 0x80000000u);
    u32 pix = (u32)i & 0xFFFFu;
    keys[i] = ((u64)k << 16) | (u64)(0xFFFFu - pix);
}

// ---------------------------------------------------------------------------
// K2 (fused): blocks 0-7 = per-batch exact top-k (radix select with
// wave-aggregated histograms) + desc bitonic + spatial re-sort;
// blocks 8-15 = spatial sort of point_coords.
__global__ __launch_bounds__(1024) void topk_sortpc_k(const u64* __restrict__ keys,
                                                      const float* __restrict__ pc,
                                                      u32* __restrict__ stash,
                                                      u32* __restrict__ pixSorted,
                                                      u32* __restrict__ pcSorted) {
    __shared__ u32 hist[256];
    __shared__ u32 scanb[256];
    __shared__ u64 sel[NN];
    __shared__ u32 s_digit, s_rem, s_cnt;
    const int t = threadIdx.x;
    const int lane = t & 63;
    if (blockIdx.x < 8) {
        const int b = blockIdx.x;
        const u64* kb = keys + (size_t)b * HWV;
        u64 prefix = 0ULL;
        u32 remaining = NN;
        for (int r = 0; r < 6; ++r) {
            int shift = 40 - 8 * r;
            if (t < 256) hist[t] = 0u;
            __syncthreads();
            for (int i = t; i < HWV; i += 1024) {
                u64 K = kb[i];
                bool pred = ((K >> (shift + 8)) == prefix);
                u32 dig = (u32)((K >> shift) & 0xFFULL);
                // wave-aggregated histogram: one atomic per distinct digit
                u64 active = __ballot(pred);
                while (active) {
                    int lead = __ffsll((long long)active) - 1;
                    u32 dl = (u32)__shfl((int)dig, lead);
                    u64 same = __ballot(pred && dig == dl);
                    if (lane == lead) atomicAdd(&hist[dl], (u32)__popcll(same));
                    active &= ~same;
                }
            }
            __syncthreads();
            if (t < 256) scanb[t] = hist[t];
            __syncthreads();
            for (int off = 1; off < 256; off <<= 1) {   // suffix sums
                u32 v = 0;
                if (t < 256) { v = scanb[t]; if (t + off < 256) v += scanb[t + off]; }
                __syncthreads();
                if (t < 256) scanb[t] = v;
                __syncthreads();
            }
            if (t < 256) {
                u32 ge = scanb[t];
                u32 gt = (t < 255) ? scanb[t + 1] : 0u;
                if (ge >= remaining && gt < remaining) { s_digit = (u32)t; s_rem = remaining - gt; }
            }
            __syncthreads();
            prefix = (prefix << 8) | (u64)s_digit;
            remaining = s_rem;
            __syncthreads();
        }
        if (t == 0) s_cnt = 0u;
        __syncthreads();
        for (int i = t; i < HWV; i += 1024) {
            u64 K = kb[i];
            if (K >= prefix) { u32 p = atomicAdd(&s_cnt, 1u); sel[p] = K; }
        }
        __syncthreads();
        for (int k = 2; k <= NN; k <<= 1) {           // bitonic desc
            for (int j = k >> 1; j > 0; j >>= 1) {
                for (int i = t; i < NN; i += 1024) {
                    int l = i ^ j;
                    if (l > i) {
                        u64 a = sel[i], c = sel[l];
                        bool asc = ((i & k) == 0);
                        if ((a < c) == asc) { sel[i] = c; sel[l] = a; }
                    }
                }
                __syncthreads();
            }
        }
        u32 myPk[4];
        #pragma unroll
        for (int q = 0; q < 4; ++q) {
            int r = t + q * 1024;
            u32 pix = 0xFFFFu - (u32)(sel[r] & 0xFFFFULL);
            stash[b * NN + r] = pix;
            myPk[q] = (pix << 12) | (u32)r;
        }
        __syncthreads();
        u32* arr = (u32*)sel;
        #pragma unroll
        for (int q = 0; q < 4; ++q) arr[t + q * 1024] = myPk[q];
        __syncthreads();
        for (int k = 2; k <= NN; k <<= 1) {           // bitonic asc (spatial)
            for (int j = k >> 1; j > 0; j >>= 1) {
                for (int i = t; i < NN; i += 1024) {
                    int l = i ^ j;
                    if (l > i) {
                        u32 a = arr[i], c = arr[l];
                        bool up = ((i & k) == 0);
                        if ((a > c) == up) { arr[i] = c; arr[l] = a; }
                    }
                }
                __syncthreads();
            }
        }
        #pragma unroll
        for (int q = 0; q < 4; ++q) { int j = t + q * 1024; pixSorted[b * NN + j] = arr[j]; }
    } else {
        const int b = blockIdx.x - 8;
        u32* arr = (u32*)sel;
        for (int n = t; n < NN; n += 1024) {
            float gx = pc[((size_t)b * NN + n) * 2 + 0];
            float gy = pc[((size_t)b * NN + n) * 2 + 1];
            float fx = gx * 256.0f - 0.5f;
            float fy = gy * 256.0f - 0.5f;
            int x0 = (int)floorf(fx), y0 = (int)floorf(fy);
            int xc = min(max(x0, 0), 255), yc = min(max(y0, 0), 255);
            arr[n] = ((u32)(yc * 256 + xc) << 12) | (u32)n;
        }
        __syncthreads();
        for (int k = 2; k <= NN; k <<= 1) {
            for (int j = k >> 1; j > 0; j >>= 1) {
                for (int i = t; i < NN; i += 1024) {
                    int l = i ^ j;
                    if (l > i) {
                        u32 a = arr[i], c = arr[l];
                        bool up = ((i & k) == 0);
                        if ((a > c) == up) { arr[i] = c; arr[l] = a; }
                    }
                }
                __syncthreads();
            }
        }
        for (int n = t; n < NN; n += 1024) pcSorted[b * NN + n] = arr[n];
    }
}

// ---------------------------------------------------------------------------
// K3: band-fused gather. Block = (band of 16 rows, 16-channel group, b).
// Both point sets of the band are processed inside the SAME plane loop, so
// each fm plane-band slice (~18KB, fits L1) is fetched from HBM once and
// reused by both gathers. Weights-zero trick keeps control flow uniform.
template<int DO_L, int DO_S>
__global__ __launch_bounds__(256) void fused_gather_k(const float* __restrict__ fm,
                                                      const float* __restrict__ pc,
                                                      const u32* __restrict__ pixSorted,
                                                      const u32* __restrict__ pcSorted,
                                                      float* __restrict__ outLp,
                                                      float* __restrict__ outS) {
    __shared__ float ltile[256][CG + 1];
    __shared__ float stile[256][CG + 1];
    __shared__ u32 lrank[256];
    __shared__ u32 snn[256];
    const int b = blockIdx.z, c0 = blockIdx.y * CG, band = blockIdx.x;
    const int t = threadIdx.x;
    const u32 keyLo = (u32)band << 24, keyHi = (u32)(band + 1) << 24;
    u32 loL = 0, cL = 0, loS = 0, cS = 0;
    if (DO_L) {
        const u32* a = pixSorted + b * NN;
        loL = lbound(a, NN, keyLo);
        cL = lbound(a, NN, keyHi) - loL;
    }
    if (DO_S) {
        const u32* a = pcSorted + b * NN;
        loS = lbound(a, NN, keyLo);
        cS = lbound(a, NN, keyHi) - loS;
    }
    u32 itersL = (cL + 255) >> 8, itersS = (cS + 255) >> 8;
    u32 iters = itersL > itersS ? itersL : itersS;
    const float* planes = fm + ((size_t)b * CC + c0) * HWV;
    for (u32 it = 0; it < iters; ++it) {
        // ---- local-point setup (weights 0 when no point) ----
        int o0 = 0, o1 = 0, o2 = 0;
        float w0 = 0, w1 = 0, w2 = 0, w3 = 0, wr2 = 0, invc = 0;
        if (DO_L) {
            u32 jl = it * 256 + (u32)t;
            if (jl < cL) {
                u32 packed = pixSorted[b * NN + loL + jl];
                u32 pix = packed >> 12;
                lrank[t] = packed & 0xFFFu;
                int yi = (int)(pix >> 8), xi = (int)(pix & 255u);
                // replicate the reference float pipeline exactly
                float cy = (float)yi / 255.0f;
                float cx = (float)xi / 255.0f;
                int x = (int)(cx * 255.0f);
                int y = (int)(cy * 255.0f);
                int x_min = max(x - 1, 0), x_max = min(x + 2, WW);
                int y_min = max(y - 1, 0), y_max = min(y + 2, HH);
                int xb = min(x_min, WW - 4);
                w0 = (xb + 0 >= x_min && xb + 0 < x_max) ? 1.0f : 0.0f;
                w1 = (xb + 1 >= x_min && xb + 1 < x_max) ? 1.0f : 0.0f;
                w2 = (xb + 2 >= x_min && xb + 2 < x_max) ? 1.0f : 0.0f;
                w3 = (xb + 3 >= x_min && xb + 3 < x_max) ? 1.0f : 0.0f;
                wr2 = (y_min + 2 < y_max) ? 1.0f : 0.0f;
                o0 = y_min * WW + xb;
                o1 = o0 + WW;
                o2 = min(y_min + 2, HH - 1) * WW + xb;
                invc = 1.0f / (float)((x_max - x_min) * (y_max - y_min));
            }
        }
        // ---- sample-point setup ----
        int so0 = 0, so1 = 0;
        float wv0 = 0, wv1 = 0, wr0 = 0, wr1 = 0;
        if (DO_S) {
            u32 js = it * 256 + (u32)t;
            if (js < cS) {
                u32 packed = pcSorted[b * NN + loS + js];
                u32 n = packed & 0xFFFu;
                snn[t] = n;
                float gx = pc[((size_t)b * NN + n) * 2 + 0];
                float gy = pc[((size_t)b * NN + n) * 2 + 1];
                float fx = gx * 256.0f - 0.5f;   // power-of-2 mul: exact
                float fy = gy * 256.0f - 0.5f;
                float fx0 = floorf(fx), fy0 = floorf(fy);
                int x0 = (int)fx0, y0 = (int)fy0;
                float wx = fx - fx0, wy = fy - fy0;
                int xb = min(max(x0, 0), WW - 2);
                if (x0 < 0)            { wv0 = wx;        wv1 = 0.0f; }
                else if (x0 >= WW - 1) { wv0 = 0.0f;      wv1 = 1.0f - wx; }
                else                   { wv0 = 1.0f - wx; wv1 = wx; }
                wr0 = (y0 >= 0)     ? (1.0f - wy) : 0.0f;
                wr1 = (y0 + 1 < HH) ? wy          : 0.0f;
                int yc0 = min(max(y0, 0), HH - 1);
                int yc1 = min(max(y0 + 1, 0), HH - 1);
                so0 = yc0 * WW + xb;
                so1 = yc1 * WW + xb;
            }
        }
        // ---- shared plane loop: one HBM pass serves both sets (L1 reuse) ----
        #pragma unroll 4
        for (int j = 0; j < CG; ++j) {
            const float* p = planes + (size_t)j * HWV;
            if (DO_L) {
                float s0 = p[o0] * w0 + p[o0 + 1] * w1 + p[o0 + 2] * w2 + p[o0 + 3] * w3;
                float s1 = p[o1] * w0 + p[o1 + 1] * w1 + p[o1 + 2] * w2 + p[o1 + 3] * w3;
                float s2 = p[o2] * w0 + p[o2 + 1] * w1 + p[o2 + 2] * w2 + p[o2 + 3] * w3;
                ltile[t][j] = (s0 + s1 + wr2 * s2) * invc;
            }
            if (DO_S) {
                stile[t][j] = wr0 * (p[so0] * wv0 + p[so0 + 1] * wv1)
                            + wr1 * (p[so1] * wv0 + p[so1 + 1] * wv1);
            }
        }
        __syncthreads();
        if (DO_L) {
            u32 rem = (it * 256 < cL) ? (cL - it * 256) : 0u;
            u32 cnt = rem < 256u ? rem : 256u;
            for (u32 idx = t; idx < cnt * CG; idx += 256) {
                u32 pp = idx >> 4, k = idx & (CG - 1);
                outLp[((size_t)b * NN + lrank[pp]) * CC + c0 + k] = ltile[pp][k];
            }
        }
        if (DO_S) {
            u32 rem = (it * 256 < cS) ? (cS - it * 256) : 0u;
            u32 cnt = rem < 256u ? rem : 256u;
            for (u32 idx = t; idx < cnt * CG; idx += 256) {
                u32 pp = idx >> 4, k = idx & (CG - 1);
                outS[((size_t)b * NN + snn[pp]) * CC + c0 + k] = stile[pp][k];
            }
        }
        __syncthreads();
    }
}

// ---------------------------------------------------------------------------
// K4: plain tile transpose outLp[b][r][c] -> outL[b][c][r].
__global__ __launch_bounds__(256) void transpose_k(const float* __restrict__ outLp,
                                                   float* __restrict__ outL) {
    __shared__ float tile[256][33];
    const int b = blockIdx.z, c0 = blockIdx.y * 32, r0 = blockIdx.x * 256;
    const int t = threadIdx.x;
    for (int idx = t; idx < 8192; idx += 256) {
        int p = idx >> 5, k = idx & 31;
        tile[p][k] = outLp[((size_t)b * NN + r0 + p) * CC + c0 + k];
    }
    __syncthreads();
    for (int idx = t; idx < 8192; idx += 256) {
        int cl = idx >> 8, col = idx & 255;
        outL[((size_t)b * CC + c0 + cl) * NN + r0 + col] = tile[col][cl];
    }
}

// ---------------------------------------------------------------------------
// K5 (LAST): coords (seg2) + idx (seg3, in-place u32 stash -> f32).
__global__ void emit_k(const u32* __restrict__ stash, float* __restrict__ outCoord,
                       float* __restrict__ outIdx) {
    int i = blockIdx.x * blockDim.x + threadIdx.x;   // 0..32767
    u32 p = stash[i];
    u32 yi = p >> 8, xi = p & 255u;
    outCoord[(size_t)i * 2 + 0] = (float)yi / 255.0f;
    outCoord[(size_t)i * 2 + 1] = (float)xi / 255.0f;
    outIdx[i] = (float)p;   // exact: p < 2^24
}

extern "C" void kernel_launch(void* const* d_in, const int* in_sizes, int n_in,
                              void* d_out, int out_size, void* d_ws, size_t ws_size,
                              hipStream_t stream) {
    const float* fm = (const float*)d_in[0];   // (8,256,256,256) f32
    const float* pm = (const float*)d_in[1];   // (8,1,256,256) f32
    const int*   em = (const int*)d_in[2];     // (8,256,256) i32
    const float* pc = (const float*)d_in[3];   // (8,4096,2) f32
    (void)in_sizes; (void)n_in; (void)out_size;

    float* out      = (float*)d_out;
    float* outL     = out;                         // local_feats (8,256,4096)
    float* outS     = out + (size_t)8388608;       // sampled     (8,4096,256)
    float* outCoord = out + (size_t)16777216;      // coords      (8,4096,2)
    float* outIdx   = out + (size_t)16842752;      // idx         (8,4096)

    // Scratch: keys (4MB) at seg1 head (dead after topk, overwritten by outS);
    // pixSorted+pcSorted in seg2 (overwritten last by emit); stash in seg3
    // (in-place converted by emit, the final kernel).
    u64* keys      = (u64*)outS;
    u32* pixSorted = (u32*)outCoord;
    u32* pcSorted  = pixSorted + 32768;
    u32* stash     = (u32*)outIdx;

    const size_t outLp_bytes = (size_t)8 * NN * CC * 4;   // 33554432
    bool ws_ok = ws_size >= outLp_bytes;
    float* outLp = ws_ok ? (float*)d_ws : outS;

    hipLaunchKernelGGL(build_keys_k,  dim3(2048), dim3(256),  0, stream, pm, em, keys);
    hipLaunchKernelGGL(topk_sortpc_k, dim3(16),   dim3(1024), 0, stream, keys, pc, stash, pixSorted, pcSorted);
    if (ws_ok) {
        // fm read once: both gathers fused, outLp in d_ws.
        hipLaunchKernelGGL((fused_gather_k<1, 1>), dim3(NBAND, CC / CG, 8), dim3(256), 0, stream,
                           fm, pc, pixSorted, pcSorted, outLp, outS);
        hipLaunchKernelGGL(transpose_k, dim3(16, 8, 8), dim3(256), 0, stream, outLp, outL);
    } else {
        // fallback (ws too small): sequential, outLp aliases seg1 then is
        // overwritten by the sample pass (round-6 semantics).
        hipLaunchKernelGGL((fused_gather_k<1, 0>), dim3(NBAND, CC / CG, 8), dim3(256), 0, stream,
                           fm, pc, pixSorted, pcSorted, outS, outS);
        hipLaunchKernelGGL(transpose_k, dim3(16, 8, 8), dim3(256), 0, stream, outS, outL);
        hipLaunchKernelGGL((fused_gather_k<0, 1>), dim3(NBAND, CC / CG, 8), dim3(256), 0, stream,
                           fm, pc, pixSorted, pcSorted, outS, outS);
    }
    hipLaunchKernelGGL(emit_k, dim3(128), dim3(256), 0, stream, stash, outCoord, outIdx);
}